// Round 1
// baseline (292.732 us; speedup 1.0000x reference)
//
#include <hip/hip_runtime.h>
#include <hip/hip_bf16.h>
#include <math.h>

#define B_  4
#define S_  4096
#define H_  8
#define D_  64
#define HD_ 512
#define NC_ 128
#define L_  32
#define NG_ 192

__device__ __forceinline__ float sigm(float v) { return 1.f / (1.f + __expf(-v)); }

// ---------------- K1: per-chunk sums of x over s, per (b, hd) ----------------
__global__ __launch_bounds__(HD_) void k_chunk_sums(const float* __restrict__ x,
                                                    float* __restrict__ sums) {
  int b = blockIdx.x >> 7, c = blockIdx.x & (NC_ - 1);
  int t = threadIdx.x;
  const float* p = x + ((size_t)b * S_ + (size_t)c * L_) * HD_ + t;
  float acc = 0.f;
  #pragma unroll
  for (int i = 0; i < L_; ++i) acc += p[(size_t)i * HD_];
  sums[((size_t)b * NC_ + c) * HD_ + t] = acc;
}

// ---------------- K2: exclusive scan of chunk sums over c ----------------
__global__ __launch_bounds__(HD_) void k_scan_offsets(const float* __restrict__ sums,
                                                      float* __restrict__ offs) {
  int b = blockIdx.x, t = threadIdx.x;
  float run = 0.f;
  for (int c = 0; c < NC_; ++c) {
    size_t idx = ((size_t)b * NC_ + c) * HD_ + t;
    offs[idx] = run;
    run += sums[idx];
  }
}

// ---------------- K3: exclusive prefix + LayerNorm over (H,D) ----------------
__global__ __launch_bounds__(HD_) void k_ln(const float* __restrict__ x,
                                            const float* __restrict__ offs,
                                            const float* __restrict__ gamma,
                                            const float* __restrict__ beta,
                                            float* __restrict__ csum) {
  __shared__ float2 red[2][8];
  int b = blockIdx.x >> 7, c = blockIdx.x & (NC_ - 1);
  int t = threadIdx.x;
  float run = offs[((size_t)b * NC_ + c) * HD_ + t];
  float g = gamma[t], be = beta[t];
  const float* xp = x + ((size_t)b * S_ + (size_t)c * L_) * HD_ + t;
  float* cp = csum + ((size_t)b * S_ + (size_t)c * L_) * HD_ + t;
  for (int i = 0; i < L_; ++i) {
    float v = run, v2 = run * run;
    #pragma unroll
    for (int o = 32; o; o >>= 1) { v += __shfl_xor(v, o); v2 += __shfl_xor(v2, o); }
    if ((t & 63) == 0) red[i & 1][t >> 6] = make_float2(v, v2);
    __syncthreads();
    float s1 = 0.f, s2 = 0.f;
    #pragma unroll
    for (int w = 0; w < 8; ++w) { s1 += red[i & 1][w].x; s2 += red[i & 1][w].y; }
    float m = s1 * (1.f / HD_);
    float var = fmaf(-m, m, s2 * (1.f / HD_));
    float inv = rsqrtf(var + 1e-5f);
    cp[(size_t)i * HD_] = (run - m) * inv * g + be;
    run += xp[(size_t)i * HD_];
  }
}

// ---------------- K4: gates GEMM  [M=131072, K=128, N=192] + sigmoid/relu ----
// A[r][k] = k<64 ? x[r*64+k] : csum[r*64+k-64]   (r = (b*S+s)*H + h)
__global__ __launch_bounds__(256) void k_gates(const float* __restrict__ x,
                                               const float* __restrict__ csum,
                                               const float* __restrict__ Wh,
                                               const float* __restrict__ bh,
                                               float* __restrict__ fg,
                                               float* __restrict__ igh) {
  __shared__ float At[64 * 68];
  __shared__ float Wl[64 * NG_];
  const int t = threadIdx.x;
  const int row0 = blockIdx.x * 64;
  const int cq = t & 15, rq = t >> 4;
  float ai[4][4], af[4][4], ah[4][4];
  #pragma unroll
  for (int i = 0; i < 4; ++i)
    #pragma unroll
    for (int j = 0; j < 4; ++j) { ai[i][j] = 0.f; af[i][j] = 0.f; ah[i][j] = 0.f; }

  for (int kb = 0; kb < 2; ++kb) {
    const float* src = kb ? csum : x;
    #pragma unroll
    for (int rep = 0; rep < 4; ++rep) {
      int idx = rep * 256 + t;
      int row = idx >> 4, kq = idx & 15;
      float4 v = ((const float4*)src)[(size_t)(row0 + row) * 16 + kq];
      *(float4*)&At[row * 68 + kq * 4] = v;
    }
    #pragma unroll
    for (int rep = 0; rep < 12; ++rep) {
      int idx = rep * 256 + t;
      ((float4*)Wl)[idx] = ((const float4*)Wh)[(size_t)kb * 3072 + idx];
    }
    __syncthreads();
    #pragma unroll 4
    for (int k = 0; k < 64; ++k) {
      float a[4];
      #pragma unroll
      for (int i = 0; i < 4; ++i) a[i] = At[(rq * 4 + i) * 68 + k];
      float4 wi = *(const float4*)&Wl[k * NG_ + cq * 4];
      float4 wf = *(const float4*)&Wl[k * NG_ + 64 + cq * 4];
      float4 wh = *(const float4*)&Wl[k * NG_ + 128 + cq * 4];
      #pragma unroll
      for (int i = 0; i < 4; ++i) {
        ai[i][0] = fmaf(a[i], wi.x, ai[i][0]); ai[i][1] = fmaf(a[i], wi.y, ai[i][1]);
        ai[i][2] = fmaf(a[i], wi.z, ai[i][2]); ai[i][3] = fmaf(a[i], wi.w, ai[i][3]);
        af[i][0] = fmaf(a[i], wf.x, af[i][0]); af[i][1] = fmaf(a[i], wf.y, af[i][1]);
        af[i][2] = fmaf(a[i], wf.z, af[i][2]); af[i][3] = fmaf(a[i], wf.w, af[i][3]);
        ah[i][0] = fmaf(a[i], wh.x, ah[i][0]); ah[i][1] = fmaf(a[i], wh.y, ah[i][1]);
        ah[i][2] = fmaf(a[i], wh.z, ah[i][2]); ah[i][3] = fmaf(a[i], wh.w, ah[i][3]);
      }
    }
    __syncthreads();
  }
  float bi[4], bf4[4], bh4[4];
  #pragma unroll
  for (int j = 0; j < 4; ++j) {
    bi[j]  = bh[cq * 4 + j];
    bf4[j] = bh[64 + cq * 4 + j];
    bh4[j] = bh[128 + cq * 4 + j];
  }
  #pragma unroll
  for (int i = 0; i < 4; ++i) {
    size_t r = (size_t)row0 + rq * 4 + i;
    float4 vf, vg;
    vf.x = sigm(af[i][0] + bf4[0]); vf.y = sigm(af[i][1] + bf4[1]);
    vf.z = sigm(af[i][2] + bf4[2]); vf.w = sigm(af[i][3] + bf4[3]);
    vg.x = sigm(ai[i][0] + bi[0]) * fmaxf(ah[i][0] + bh4[0], 0.f);
    vg.y = sigm(ai[i][1] + bi[1]) * fmaxf(ah[i][1] + bh4[1], 0.f);
    vg.z = sigm(ai[i][2] + bi[2]) * fmaxf(ah[i][2] + bh4[2], 0.f);
    vg.w = sigm(ai[i][3] + bi[3]) * fmaxf(ah[i][3] + bh4[3], 0.f);
    ((float4*)fg)[r * 16 + cq]  = vf;
    ((float4*)igh)[r * 16 + cq] = vg;
  }
}

// ---------------- K5a: per-chunk composition of (fg, igh) ----------------
__global__ __launch_bounds__(HD_) void k_cell_chunk(const float* __restrict__ fg,
                                                    const float* __restrict__ igh,
                                                    float* __restrict__ cA,
                                                    float* __restrict__ cB) {
  int b = blockIdx.x >> 7, c = blockIdx.x & (NC_ - 1);
  int t = threadIdx.x;
  const float* fp = fg + ((size_t)b * S_ + (size_t)c * L_) * HD_ + t;
  const float* ip = igh + ((size_t)b * S_ + (size_t)c * L_) * HD_ + t;
  float a = 1.f, bb = 0.f;
  #pragma unroll
  for (int i = 0; i < L_; ++i) {
    float f = fp[(size_t)i * HD_], g = ip[(size_t)i * HD_];
    a *= f;
    bb = fmaf(bb, f, g);
  }
  size_t idx = ((size_t)b * NC_ + c) * HD_ + t;
  cA[idx] = a; cB[idx] = bb;
}

// ---------------- K5b: cross-chunk scan → cell at chunk entry ----------------
__global__ __launch_bounds__(HD_) void k_cell_scan(const float* __restrict__ cA,
                                                   const float* __restrict__ cB,
                                                   const float* __restrict__ initcx,
                                                   float* __restrict__ cin) {
  int b = blockIdx.x, t = threadIdx.x;
  float run = initcx[t];
  for (int c = 0; c < NC_; ++c) {
    size_t idx = ((size_t)b * NC_ + c) * HD_ + t;
    cin[idx] = run;
    run = fmaf(cA[idx], run, cB[idx]);
  }
}

// ---------------- K5c: emit cell for every s ----------------
__global__ __launch_bounds__(HD_) void k_cell_emit(const float* __restrict__ fg,
                                                   const float* __restrict__ igh,
                                                   const float* __restrict__ cin,
                                                   float* __restrict__ cell) {
  int b = blockIdx.x >> 7, c = blockIdx.x & (NC_ - 1);
  int t = threadIdx.x;
  float run = cin[((size_t)b * NC_ + c) * HD_ + t];
  const float* fp = fg + ((size_t)b * S_ + (size_t)c * L_) * HD_ + t;
  const float* ip = igh + ((size_t)b * S_ + (size_t)c * L_) * HD_ + t;
  float* cp = cell + ((size_t)b * S_ + (size_t)c * L_) * HD_ + t;
  #pragma unroll
  for (int i = 0; i < L_; ++i) {
    run = fmaf(fp[(size_t)i * HD_], run, ip[(size_t)i * HD_]);
    cp[(size_t)i * HD_] = run;
  }
}

// ---------------- K6: og GEMM [M=131072, K=128, N=64] + sigmoid * cell ------
__global__ __launch_bounds__(256) void k_og(const float* __restrict__ x,
                                            const float* __restrict__ cell,
                                            const float* __restrict__ Wo,
                                            const float* __restrict__ bo,
                                            float* __restrict__ out) {
  __shared__ float At[64 * 68];
  __shared__ float Wl[64 * 64];
  const int t = threadIdx.x;
  const int row0 = blockIdx.x * 64;
  const int cq = t & 15, rq = t >> 4;
  float acc[4][4];
  #pragma unroll
  for (int i = 0; i < 4; ++i)
    #pragma unroll
    for (int j = 0; j < 4; ++j) acc[i][j] = 0.f;

  for (int kb = 0; kb < 2; ++kb) {
    const float* src = kb ? cell : x;
    #pragma unroll
    for (int rep = 0; rep < 4; ++rep) {
      int idx = rep * 256 + t;
      int row = idx >> 4, kq = idx & 15;
      float4 v = ((const float4*)src)[(size_t)(row0 + row) * 16 + kq];
      *(float4*)&At[row * 68 + kq * 4] = v;
    }
    #pragma unroll
    for (int rep = 0; rep < 4; ++rep) {
      int idx = rep * 256 + t;
      ((float4*)Wl)[idx] = ((const float4*)Wo)[(size_t)kb * 1024 + idx];
    }
    __syncthreads();
    #pragma unroll 4
    for (int k = 0; k < 64; ++k) {
      float a[4];
      #pragma unroll
      for (int i = 0; i < 4; ++i) a[i] = At[(rq * 4 + i) * 68 + k];
      float4 w = *(const float4*)&Wl[k * 64 + cq * 4];
      #pragma unroll
      for (int i = 0; i < 4; ++i) {
        acc[i][0] = fmaf(a[i], w.x, acc[i][0]); acc[i][1] = fmaf(a[i], w.y, acc[i][1]);
        acc[i][2] = fmaf(a[i], w.z, acc[i][2]); acc[i][3] = fmaf(a[i], w.w, acc[i][3]);
      }
    }
    __syncthreads();
  }
  float b4[4];
  #pragma unroll
  for (int j = 0; j < 4; ++j) b4[j] = bo[cq * 4 + j];
  #pragma unroll
  for (int i = 0; i < 4; ++i) {
    size_t r = (size_t)row0 + rq * 4 + i;
    float4 cv = ((const float4*)cell)[r * 16 + cq];
    float4 o;
    o.x = sigm(acc[i][0] + b4[0]) * cv.x;
    o.y = sigm(acc[i][1] + b4[1]) * cv.y;
    o.z = sigm(acc[i][2] + b4[2]) * cv.z;
    o.w = sigm(acc[i][3] + b4[3]) * cv.w;
    ((float4*)out)[r * 16 + cq] = o;
  }
}

extern "C" void kernel_launch(void* const* d_in, const int* in_sizes, int n_in,
                              void* d_out, int out_size, void* d_ws, size_t ws_size,
                              hipStream_t stream) {
  const float* x      = (const float*)d_in[0];
  const float* W_hid  = (const float*)d_in[1];
  const float* b_hid  = (const float*)d_in[2];
  const float* W_og   = (const float*)d_in[3];
  const float* b_og   = (const float*)d_in[4];
  const float* gamma  = (const float*)d_in[5];
  const float* beta   = (const float*)d_in[6];
  const float* initcx = (const float*)d_in[7];
  float* out = (float*)d_out;
  float* ws  = (float*)d_ws;

  const size_t SMALL = (size_t)B_ * NC_ * HD_;  // 262144 floats
  const size_t BIG   = (size_t)B_ * S_ * HD_;   // 8388608 floats
  float* sums = ws;
  float* offs = sums + SMALL;
  float* cA   = offs + SMALL;
  float* cBv  = cA + SMALL;
  float* cin  = cBv + SMALL;
  float* csum = cin + SMALL;
  float* fgv  = csum + BIG;
  float* ighv = fgv + BIG;
  float* cell = csum;  // csum dead after k_gates; reuse for cell

  k_chunk_sums <<<B_ * NC_, HD_, 0, stream>>>(x, sums);
  k_scan_offsets<<<B_,       HD_, 0, stream>>>(sums, offs);
  k_ln         <<<B_ * NC_, HD_, 0, stream>>>(x, offs, gamma, beta, csum);
  k_gates      <<<2048,     256, 0, stream>>>(x, csum, W_hid, b_hid, fgv, ighv);
  k_cell_chunk <<<B_ * NC_, HD_, 0, stream>>>(fgv, ighv, cA, cBv);
  k_cell_scan  <<<B_,       HD_, 0, stream>>>(cA, cBv, initcx, cin);
  k_cell_emit  <<<B_ * NC_, HD_, 0, stream>>>(fgv, ighv, cin, cell);
  k_og         <<<2048,     256, 0, stream>>>(x, cell, W_og, b_og, out);
}

// Round 2
// 218.953 us; speedup vs baseline: 1.3370x; 1.3370x over previous
//
#include <hip/hip_runtime.h>
#include <math.h>

#define S_   4096
#define H_   8
#define D_   64
#define HD_  512
#define NCH  256   // chunks per batch
#define LCH  16    // seq steps per chunk
#define RC   128   // rows per chunk = LCH*H_

typedef __bf16 bf16x8 __attribute__((ext_vector_type(8)));
typedef float  f32x4  __attribute__((ext_vector_type(4)));

__device__ __forceinline__ float sigm(float v) { return 1.f / (1.f + __expf(-v)); }

// ---------------- K0: transpose weights to bf16 [n][k] ----------------
__global__ __launch_bounds__(256) void k_wt(const float* __restrict__ Wh,
                                            const float* __restrict__ Wo,
                                            __bf16* __restrict__ Wth,
                                            __bf16* __restrict__ Wto) {
  int idx = blockIdx.x * 256 + threadIdx.x;   // 0..32767
  if (idx < 24576) {
    int k = idx / 192, n = idx % 192;
    Wth[n * 128 + k] = (__bf16)Wh[idx];
  } else {
    int j = idx - 24576;                       // 0..8191, W_og[k][n], n<64
    int k = j >> 6, n = j & 63;
    Wto[n * 128 + k] = (__bf16)Wo[j];
  }
}

// ---------------- K1: per-chunk sums of x ----------------
__global__ __launch_bounds__(512) void k_chunk_sums(const float* __restrict__ x,
                                                    float* __restrict__ sums) {
  const int b = blockIdx.x >> 8, c = blockIdx.x & 255;
  const int t = threadIdx.x;
  const float* p = x + ((size_t)b * S_ + c * LCH) * HD_ + t;
  float acc = 0.f;
  #pragma unroll
  for (int i = 0; i < LCH; ++i) acc += p[(size_t)i * HD_];
  sums[((size_t)b * NCH + c) * HD_ + t] = acc;
}

// ---------------- K2: exclusive scan of chunk sums (in-place) ----------------
__global__ __launch_bounds__(512) void k_scan_offsets(float* __restrict__ sums) {
  const int b = blockIdx.x, t = threadIdx.x;
  float run = 0.f;
  for (int c = 0; c < NCH; ++c) {
    size_t idx = ((size_t)b * NCH + c) * HD_ + t;
    float v = sums[idx];
    sums[idx] = run;
    run += v;
  }
}

// ---------------- K3: prefix + LayerNorm, emit packed bf16 A = [x | ln] -----
__global__ __launch_bounds__(512) void k_ln(const float* __restrict__ x,
                                            const float* __restrict__ offs,
                                            const float* __restrict__ gamma,
                                            const float* __restrict__ beta,
                                            __bf16* __restrict__ Abf) {
  __shared__ float2 red[2][8];
  const int b = blockIdx.x >> 8, c = blockIdx.x & 255;
  const int t = threadIdx.x;
  float run = offs[((size_t)b * NCH + c) * HD_ + t];
  const float g = gamma[t], be = beta[t];
  const size_t xbase = ((size_t)b * S_ + c * LCH) * HD_ + t;
  const int h = t >> 6, d = t & 63;
  float xv = x[xbase];
  for (int i = 0; i < LCH; ++i) {
    float xn = (i < LCH - 1) ? x[xbase + (size_t)(i + 1) * HD_] : 0.f;
    float v = run, v2 = run * run;
    #pragma unroll
    for (int o = 32; o; o >>= 1) { v += __shfl_xor(v, o); v2 += __shfl_xor(v2, o); }
    if ((t & 63) == 0) red[i & 1][t >> 6] = make_float2(v, v2);
    __syncthreads();
    float s1 = 0.f, s2 = 0.f;
    #pragma unroll
    for (int w = 0; w < 8; ++w) { s1 += red[i & 1][w].x; s2 += red[i & 1][w].y; }
    float m = s1 * (1.f / HD_);
    float var = fmaf(-m, m, s2 * (1.f / HD_));
    float inv = rsqrtf(var + 1e-5f);
    size_t r = ((size_t)b * S_ + c * LCH + i) * H_ + h;
    Abf[r * 128 + 64 + d] = (__bf16)((run - m) * inv * g + be);
    Abf[r * 128 + d] = (__bf16)xv;
    run += xv;
    xv = xn;
  }
}

// ---------------- K4: gates MFMA GEMM + activations + chunk compose ----------
// Block = one chunk: 128 rows (16 s x 8 h), N=192, K=128. 256 thr = 4 waves.
__global__ __launch_bounds__(256) void k_gates(const __bf16* __restrict__ Abf,
                                               const __bf16* __restrict__ Wt,
                                               const float* __restrict__ bh,
                                               float* __restrict__ fg,
                                               float* __restrict__ igh,
                                               float* __restrict__ cA,
                                               float* __restrict__ cB) {
  __shared__ float fgl[RC * 68];
  __shared__ float ighl[RC * 68];
  const int t = threadIdx.x;
  const int wave = t >> 6, lane = t & 63;
  const int quad = lane >> 4, l16 = lane & 15;
  const int r0 = blockIdx.x * RC;

  f32x4 acc[2][12];
  #pragma unroll
  for (int i = 0; i < 2; ++i)
    #pragma unroll
    for (int j = 0; j < 12; ++j) acc[i][j] = (f32x4){0.f, 0.f, 0.f, 0.f};

  #pragma unroll
  for (int ks = 0; ks < 4; ++ks) {
    bf16x8 bfrag[12];
    #pragma unroll
    for (int nt = 0; nt < 12; ++nt)
      bfrag[nt] = *(const bf16x8*)(Wt + (nt * 16 + l16) * 128 + ks * 32 + quad * 8);
    #pragma unroll
    for (int mi = 0; mi < 2; ++mi) {
      int mt = wave * 2 + mi;
      bf16x8 afrag = *(const bf16x8*)(Abf + (size_t)(r0 + mt * 16 + l16) * 128 + ks * 32 + quad * 8);
      #pragma unroll
      for (int nt = 0; nt < 12; ++nt)
        acc[mi][nt] = __builtin_amdgcn_mfma_f32_16x16x32_bf16(afrag, bfrag[nt], acc[mi][nt], 0, 0, 0);
    }
  }

  // epilogue: bias + activations -> LDS (col n, n+64, n+128 live in same lane)
  #pragma unroll
  for (int mi = 0; mi < 2; ++mi) {
    int mt = wave * 2 + mi;
    #pragma unroll
    for (int nt = 0; nt < 4; ++nt) {
      int d = nt * 16 + l16;
      float bi = bh[d], bf = bh[64 + d], bhv = bh[128 + d];
      #pragma unroll
      for (int r = 0; r < 4; ++r) {
        int row = mt * 16 + quad * 4 + r;
        float ip = acc[mi][nt][r] + bi;
        float fp = acc[mi][nt + 4][r] + bf;
        float hp = acc[mi][nt + 8][r] + bhv;
        fgl[row * 68 + d] = sigm(fp);
        ighl[row * 68 + d] = sigm(ip) * fmaxf(hp, 0.f);
      }
    }
  }
  __syncthreads();

  // coalesced float4 writes LDS -> global
  #pragma unroll
  for (int rep = 0; rep < 8; ++rep) {
    int idx = rep * 256 + t;
    int row = idx >> 4, c4 = idx & 15;
    float4 vf = *(const float4*)&fgl[row * 68 + c4 * 4];
    float4 vg = *(const float4*)&ighl[row * 68 + c4 * 4];
    ((float4*)fg)[(size_t)(r0 + row) * 16 + c4] = vf;
    ((float4*)igh)[(size_t)(r0 + row) * 16 + c4] = vg;
  }

  // fused chunk-local scan composition
  #pragma unroll
  for (int p = 0; p < 2; ++p) {
    int hd = p * 256 + t;
    int h = hd >> 6, d = hd & 63;
    float a = 1.f, bb = 0.f;
    #pragma unroll
    for (int s = 0; s < LCH; ++s) {
      float f = fgl[(s * 8 + h) * 68 + d];
      float g = ighl[(s * 8 + h) * 68 + d];
      a *= f;
      bb = fmaf(bb, f, g);
    }
    cA[(size_t)blockIdx.x * 512 + hd] = a;
    cB[(size_t)blockIdx.x * 512 + hd] = bb;
  }
}

// ---------------- K5: cross-chunk scan (in-place: cA becomes cin) ------------
__global__ __launch_bounds__(512) void k_cell_scan(float* __restrict__ cA,
                                                   const float* __restrict__ cB,
                                                   const float* __restrict__ initcx) {
  const int b = blockIdx.x, t = threadIdx.x;
  float run = initcx[t];
  for (int c = 0; c < NCH; ++c) {
    size_t idx = ((size_t)b * NCH + c) * HD_ + t;
    float a = cA[idx], bb = cB[idx];
    cA[idx] = run;
    run = fmaf(a, run, bb);
  }
}

// ---------------- K6: fused cell-emit + og MFMA GEMM + out = og*cell ---------
__global__ __launch_bounds__(256) void k_og(const __bf16* __restrict__ Abf,
                                            const float* __restrict__ fg,
                                            const float* __restrict__ igh,
                                            const float* __restrict__ cin,
                                            const __bf16* __restrict__ Wt,
                                            const float* __restrict__ bo,
                                            float* __restrict__ out) {
  __shared__ float cl[RC * 68];
  const int t = threadIdx.x;
  const int wave = t >> 6, lane = t & 63;
  const int quad = lane >> 4, l16 = lane & 15;
  const int r0 = blockIdx.x * RC;

  // emit cell for this chunk into LDS
  #pragma unroll
  for (int p = 0; p < 2; ++p) {
    int hd = p * 256 + t;
    int h = hd >> 6, d = hd & 63;
    float run = cin[(size_t)blockIdx.x * 512 + hd];
    #pragma unroll
    for (int s = 0; s < LCH; ++s) {
      size_t row = (size_t)r0 + s * 8 + h;
      run = fmaf(fg[row * 64 + d], run, igh[row * 64 + d]);
      cl[(s * 8 + h) * 68 + d] = run;
    }
  }
  __syncthreads();

  f32x4 acc[2][4];
  #pragma unroll
  for (int i = 0; i < 2; ++i)
    #pragma unroll
    for (int j = 0; j < 4; ++j) acc[i][j] = (f32x4){0.f, 0.f, 0.f, 0.f};

  #pragma unroll
  for (int ks = 0; ks < 4; ++ks) {
    bf16x8 bfrag[4];
    #pragma unroll
    for (int nt = 0; nt < 4; ++nt)
      bfrag[nt] = *(const bf16x8*)(Wt + (nt * 16 + l16) * 128 + ks * 32 + quad * 8);
    #pragma unroll
    for (int mi = 0; mi < 2; ++mi) {
      int mt = wave * 2 + mi;
      bf16x8 afrag;
      if (ks < 2) {
        afrag = *(const bf16x8*)(Abf + (size_t)(r0 + mt * 16 + l16) * 128 + ks * 32 + quad * 8);
      } else {
        int rowl = mt * 16 + l16;
        const float* src = &cl[rowl * 68 + (ks - 2) * 32 + quad * 8];
        #pragma unroll
        for (int j = 0; j < 8; ++j) afrag[j] = (__bf16)src[j];
      }
      #pragma unroll
      for (int nt = 0; nt < 4; ++nt)
        acc[mi][nt] = __builtin_amdgcn_mfma_f32_16x16x32_bf16(afrag, bfrag[nt], acc[mi][nt], 0, 0, 0);
    }
  }

  #pragma unroll
  for (int mi = 0; mi < 2; ++mi) {
    int mt = wave * 2 + mi;
    #pragma unroll
    for (int nt = 0; nt < 4; ++nt) {
      int d = nt * 16 + l16;
      float bv = bo[d];
      #pragma unroll
      for (int r = 0; r < 4; ++r) {
        int rowl = mt * 16 + quad * 4 + r;
        float og = sigm(acc[mi][nt][r] + bv);
        out[(size_t)(r0 + rowl) * 64 + d] = og * cl[rowl * 68 + d];
      }
    }
  }
}

extern "C" void kernel_launch(void* const* d_in, const int* in_sizes, int n_in,
                              void* d_out, int out_size, void* d_ws, size_t ws_size,
                              hipStream_t stream) {
  const float* x      = (const float*)d_in[0];
  const float* W_hid  = (const float*)d_in[1];
  const float* b_hid  = (const float*)d_in[2];
  const float* W_og   = (const float*)d_in[3];
  const float* b_og   = (const float*)d_in[4];
  const float* gamma  = (const float*)d_in[5];
  const float* beta   = (const float*)d_in[6];
  const float* initcx = (const float*)d_in[7];
  float* out = (float*)d_out;
  float* ws  = (float*)d_ws;

  // ws layout (floats): buf0 0.5M | buf1 0.5M | Abf 8M(bf16 16M) | fg 8M | igh 8M | Wt
  float*  buf0 = ws;                         // sums/offs, then cA/cin
  float*  buf1 = ws + 524288;                // cB
  __bf16* Abf  = (__bf16*)(ws + 1048576);    // [M][128] bf16
  float*  fgv  = ws + 1048576 + 8388608;
  float*  ighv = fgv + 8388608;
  __bf16* Wth  = (__bf16*)(ighv + 8388608);  // [192][128] bf16
  __bf16* Wto  = Wth + 24576;                // [64][128] bf16

  k_wt         <<<128,  256, 0, stream>>>(W_hid, W_og, Wth, Wto);
  k_chunk_sums <<<1024, 512, 0, stream>>>(x, buf0);
  k_scan_offsets<<<4,   512, 0, stream>>>(buf0);
  k_ln         <<<1024, 512, 0, stream>>>(x, buf0, gamma, beta, Abf);
  k_gates      <<<1024, 256, 0, stream>>>(Abf, Wth, b_hid, fgv, ighv, buf0, buf1);
  k_cell_scan  <<<4,    512, 0, stream>>>(buf0, buf1, initcx);
  k_og         <<<1024, 256, 0, stream>>>(Abf, fgv, ighv, buf0, Wto, b_og, out);
}